// Round 6
// baseline (955.738 us; speedup 1.0000x reference)
//
#include <hip/hip_runtime.h>
#include <hip/hip_bf16.h>

// Fishnet round 9: software-pipelined produce/consume main_kernel.
//   Model (r6-r8): occupancy pinned at 2-3 waves/SIMD by ~200-reg footprint
//   (wf[10][2]=80 AGPRs confirmed by r8's VGPR=68 + occ jump); per-tile serial
//   latency ~10-15k cyc vs ~1.5k issue work -> latency-bound. Fix: overlap.
//   - L image double-buffered (2 x 8KB/wave, 64KB/block, still 2 blocks/CU);
//     produce(tile k+1) writes buf^1 while consume(tile k) F-MFMAs read buf.
//   - 9 produce-T iterations source-interleaved 1:1 with 8 consume-F pairs;
//     F dep-chain + ds_read latency hide under tanh/trans VALU work.
//   - one wave_lds_sync per tile (was 2); gather gets 2 tiles of cover.
//   - W cache back in registers/AGPR (r6 best variant); static grid.
//   - Ek from off[s+1] (== off[s]+cnt[s]): halves wave-init loads.
// Aux: hist/scan/scatter counting sort + per-thread Cholesky seg solve (verified).

#define N_PTS   1000000
#define DIM     64
#define INNER   16
#define OUTD    64
#define NSEG    100000
#define NTRI    136
#define NET_OUT 152
#define NB      391          // ceil(NSEG/256)
#define SEGW    7            // segments per wave in main_kernel
#define NWAVES  ((NSEG + SEGW - 1) / SEGW)
#define MAINB   ((NWAVES + 3) / 4)

typedef short bf16x8 __attribute__((ext_vector_type(8)));
typedef float f32x4  __attribute__((ext_vector_type(4)));
typedef float f32x2  __attribute__((ext_vector_type(2)));
typedef __bf16 bfv2  __attribute__((ext_vector_type(2)));

__device__ __host__ __forceinline__ constexpr int tri(int i) { return i * (i + 1) / 2; }

__device__ __forceinline__ float fast_tanh(float x) {
    float e = __expf(2.0f * x);
    return 1.0f - __fdividef(2.0f, e + 1.0f);
}
__device__ __forceinline__ float fast_softplus(float x) {
    return __logf(1.0f + __expf(x));
}
// native RNE fp32 -> bf16 (v_cvt_pk_bf16_f32 on gfx950)
__device__ __forceinline__ unsigned short cvt1(float f) {
    __bf16 h = (__bf16)f;
    return __builtin_bit_cast(unsigned short, h);
}
__device__ __forceinline__ unsigned cvt2(float a, float b) {
    f32x2 t; t[0] = a; t[1] = b;
    bfv2 h = __builtin_convertvector(t, bfv2);
    return __builtin_bit_cast(unsigned, h);
}

// in-wave LDS producer->consumer ordering (validated round 2)
__device__ __forceinline__ void wave_lds_sync() {
    __builtin_amdgcn_wave_barrier();
    __builtin_amdgcn_s_waitcnt(0xC07F);   // lgkmcnt(0)
    __builtin_amdgcn_wave_barrier();
}

__device__ __forceinline__ void ecoord(int e, int& r, int& c, bool& dg) {
    int rr = 0;
    #pragma unroll
    for (int k = 1; k < 16; ++k) rr = (e >= tri(k)) ? k : rr;
    r = rr; c = e - tri(rr); dg = (c == rr);
}

// ---------------------------------------------------------------------------
__global__ __launch_bounds__(256) void hist_kernel(const int* __restrict__ segs,
                                                   int* __restrict__ cnt,
                                                   int* __restrict__ rank)
{
    int t = blockIdx.x * 256 + threadIdx.x;
    if (t < N_PTS) rank[t] = atomicAdd(&cnt[segs[t]], 1);
}

__global__ __launch_bounds__(256) void scan_blocks(const int* __restrict__ cnt,
                                                   int* __restrict__ off,
                                                   int* __restrict__ bsum)
{
    __shared__ int sh[256];
    const int t = threadIdx.x;
    const int i = blockIdx.x * 256 + t;
    int v = (i < NSEG) ? cnt[i] : 0;
    sh[t] = v;
    __syncthreads();
    #pragma unroll
    for (int d = 1; d < 256; d <<= 1) {
        int add = (t >= d) ? sh[t - d] : 0;
        __syncthreads();
        sh[t] += add;
        __syncthreads();
    }
    if (i < NSEG) off[i] = sh[t] - v;
    if (t == 255) bsum[blockIdx.x] = sh[t];
}

__global__ __launch_bounds__(512) void scan_top(int* __restrict__ bsum)
{
    __shared__ int sh[512];
    const int t = threadIdx.x;
    int v = (t < NB) ? bsum[t] : 0;
    sh[t] = v;
    __syncthreads();
    #pragma unroll
    for (int d = 1; d < 512; d <<= 1) {
        int add = (t >= d) ? sh[t - d] : 0;
        __syncthreads();
        sh[t] += add;
        __syncthreads();
    }
    if (t < NB) bsum[t] = sh[t] - v;
}

__global__ __launch_bounds__(256) void scan_add(int* __restrict__ off,
                                                const int* __restrict__ bsum)
{
    int i = blockIdx.x * 256 + threadIdx.x;
    if (i < NSEG) off[i] += bsum[blockIdx.x];
}

__global__ __launch_bounds__(256) void scatter_kernel(const int* __restrict__ segs,
                                                      const int* __restrict__ off,
                                                      const int* __restrict__ rank,
                                                      int* __restrict__ sorted)
{
    int t = blockIdx.x * 256 + threadIdx.x;
    if (t < N_PTS) sorted[off[segs[t]] + rank[t]] = t;
}

// ---------------------------------------------------------------------------
// main: one wave per SEGW consecutive segments; 2-stage pipelined tile stream.
// ---------------------------------------------------------------------------
__global__ __launch_bounds__(256, 2)
void main_kernel(const float* __restrict__ data,
                 const int*   __restrict__ sorted,
                 const int*   __restrict__ off,
                 const float* __restrict__ W,
                 const float* __restrict__ bias,
                 float* __restrict__ Fred,
                 float* __restrict__ tred)
{
    // per wave: 2 buffers x (16 points x 256 ushorts) = 16 KB; block total 64 KB
    __shared__ __align__(16) unsigned short lds[4][2][4096];
    const int l = threadIdx.x & 63;
    const int w = threadIdx.x >> 6;
    const int c = l & 15;          // col-in-tile / D-col / A-row
    const int q = l >> 4;          // quad

    const int wave_id = blockIdx.x * 4 + w;
    const int ws0 = wave_id * SEGW;
    if (ws0 >= NSEG) return;
    const int ws1 = min(ws0 + SEGW, NSEG);

    // ---- wave-owned segment end offsets (off[s+1] == off[s]+cnt[s]) ----
    int Ek[SEGW];
    #pragma unroll
    for (int k = 0; k < SEGW; ++k) {
        const int s = ws0 + k;
        Ek[k] = (s < ws1) ? ((s + 1 < NSEG) ? off[s + 1] : N_PTS) : 0x7fffffff;
    }
    const int gend = (ws1 < NSEG) ? off[ws1] : N_PTS;
    int g = off[ws0];
    if (g >= gend) return;         // all owned segments empty

    // zero both L buffers: strict-upper stays zero forever
    #pragma unroll
    for (int u = 0; u < 64; ++u) ((unsigned*)&lds[w][0][0])[u * 64 + l] = 0u;
    wave_lds_sync();

    // ---- register-cache W fragments (B-operand layout) + bias ----
    bf16x8 wf[10][2];
    float  bT[10];
    #pragma unroll
    for (int T = 0; T < 10; ++T) {
        #pragma unroll
        for (int ks = 0; ks < 2; ++ks) {
            bf16x8 f;
            #pragma unroll
            for (int j = 0; j < 8; ++j) {
                int k = 32 * ks + 8 * q + j;
                int n = 16 * T + c;
                f[j] = (n < NET_OUT) ? (short)cvt1(W[k * NET_OUT + n]) : (short)0;
            }
            wf[T][ks] = f;
        }
        int n = 16 * T + c;
        bT[T] = (n < NET_OUT) ? bias[n] : 0.0f;
    }

    // ---- per-lane entry coords for T=1..9 (e = 16*(T-1)+c), stride 16 ----
    int rcoff[9];
    int dgmask = 0, dgoff0 = 0;
    #pragma unroll
    for (int T = 1; T <= 9; ++T) {
        int e = 16 * (T - 1) + c;
        int re, ce; bool dg;
        ecoord(e, re, ce, dg);
        rcoff[T - 1] = re * 16 + ce;
        if (dg && (T < 9 || c < 8)) {
            dgmask |= 1 << T;
            if (T <= 8) dgoff0 = re * 16 + ce;
        }
    }
    const bool v9     = (c < 8);       // T=9 valid only for c<8 (e<136)
    const bool hasdg0 = (c != 15);
    const int  qb     = q << 10;       // point (4q)*256 ushorts base
    const int  lofs   = c * 16 + (q & 1) * 8 + (q >> 1) * 256;

    // ---- running consume-side state ----
    f32x4 fa = {0.f, 0.f, 0.f, 0.f};
    f32x4 fb = {0.f, 0.f, 0.f, 0.f};
    float tcarry = 0.f;
    int a_start = 0;
    float dsv0 = 0.f, dsv1 = 0.f, dsv2 = 0.f, dsv3 = 0.f;

    // meta of the tile currently in the consume buffer
    float Pc0, Pc1, Pc2, Pc3;
    unsigned long long bmc;
    int sidc, nvc;

    auto flushC = [&](int i) {
        const int sid = __shfl(sidc, i, 64);
        const int rs = i & 3;
        float vi = (rs == 0) ? Pc0 : (rs == 1) ? Pc1 : (rs == 2) ? Pc2 : Pc3;
        float Pi = __shfl(vi, ((i >> 2) << 4) | c, 64);
        float Pe = 0.f;
        if (a_start > 0) {
            const int aa = a_start - 1, ra = aa & 3;
            float va = (ra == 0) ? Pc0 : (ra == 1) ? Pc1 : (ra == 2) ? Pc2 : Pc3;
            Pe = __shfl(va, ((aa >> 2) << 4) | c, 64);
        }
        float ts = Pi - Pe + tcarry;
        if (l < 16) tred[(size_t)sid * INNER + c] = ts;
        tcarry = 0.f;
        f32x4 ft = fa + fb;
        #pragma unroll
        for (int r = 0; r < 4; ++r) {
            const int mr = 4 * q + r;
            if (c <= mr)
                Fred[(size_t)sid * NTRI + tri(mr) + c] = ft[r];
        }
        fa = (f32x4){0.f, 0.f, 0.f, 0.f};
        fb = (f32x4){0.f, 0.f, 0.f, 0.f};
        a_start = i + 1;
    };

    // produce one T-slice of the L image into LP (a2 from net MFMA outside)
    auto prodT = [&](int T, const f32x4& a2, unsigned short* LP) {
        const bool isdg = (dgmask >> T) & 1;
        const bool st   = (T < 9 || v9) && !isdg;
        unsigned short* bp = LP + (qb + rcoff[T - 1]);
        #pragma unroll
        for (int r = 0; r < 4; ++r) {
            float v = fast_tanh(a2[r] + bT[T]);
            if (st) bp[r * 256] = cvt1(v);
            if (T <= 8) {
                if (r == 0) dsv0 = isdg ? v : dsv0;
                if (r == 1) dsv1 = isdg ? v : dsv1;
                if (r == 2) dsv2 = isdg ? v : dsv2;
                if (r == 3) dsv3 = isdg ? v : dsv3;
            }
        }
        if (T == 9 && (c == 7)) {   // second diagonal (15,15) for c==7 lanes
            unsigned short* dp9 = LP + (qb + 255);
            #pragma unroll
            for (int r = 0; r < 4; ++r) {
                float v = fast_tanh(a2[r] + bT[9]);
                dp9[r * 256] = cvt1(fast_softplus(v));
            }
        }
    };
    auto diagpost = [&](unsigned short* LP) {
        if (hasdg0) {
            unsigned short* dp0 = LP + (qb + dgoff0);
            dp0[0]   = cvt1(fast_softplus(dsv0));
            dp0[256] = cvt1(fast_softplus(dsv1));
            dp0[512] = cvt1(fast_softplus(dsv2));
            dp0[768] = cvt1(fast_softplus(dsv3));
        }
    };
    // consume one pair (full 16-point tile: i1 always valid)
    auto consPair = [&](int j, const unsigned short* LC) {
        const int i0 = 2 * j, i1 = i0 + 1;
        bf16x8 lf = *(const bf16x8*)(LC + i0 * 256 + lofs);
        const bool f0 = (bmc >> i0) & 1;
        if (!f0) {
            if (j & 1) fb = __builtin_amdgcn_mfma_f32_16x16x32_bf16(lf, lf, fb, 0, 0, 0);
            else       fa = __builtin_amdgcn_mfma_f32_16x16x32_bf16(lf, lf, fa, 0, 0, 0);
        } else {
            const bf16x8 zz = {0, 0, 0, 0, 0, 0, 0, 0};
            bf16x8 lo = (q < 2) ? lf : zz;
            fa = __builtin_amdgcn_mfma_f32_16x16x32_bf16(lo, lo, fa, 0, 0, 0);
            flushC(i0);
            bf16x8 hi = (q >= 2) ? lf : zz;
            fb = __builtin_amdgcn_mfma_f32_16x16x32_bf16(hi, hi, fb, 0, 0, 0);
        }
        if ((bmc >> i1) & 1) flushC(i1);
    };

    // ---------------- prologue: gather + produce tile 0 ----------------
    int idxA = min(g + c, gend - 1);
    {
        const int pA = sorted[idxA];
        const float* dA = data + (size_t)pA * DIM + 8 * q;
        float4 x0 = ((const float4*)dA)[0], x1 = ((const float4*)dA)[1];
        float4 x2 = ((const float4*)(dA + 32))[0], x3 = ((const float4*)(dA + 32))[1];

        const int nvA = min(16, gend - g);
        int gN = g + nvA;                       // start of tile 1
        // issue gather for tile 1
        int idxB = min(gN + c, gend - 1);
        const int pB = sorted[idxB];
        const float* dB = data + (size_t)pB * DIM + 8 * q;
        float4 y0 = ((const float4*)dB)[0], y1 = ((const float4*)dB)[1];
        float4 y2 = ((const float4*)(dB + 32))[0], y3 = ((const float4*)(dB + 32))[1];

        // meta tile 0
        {
            int segl = 0; bool flag = false;
            #pragma unroll
            for (int k = 0; k < SEGW; ++k) {
                segl += (idxA >= Ek[k]) ? 1 : 0;
                flag |= (idxA == Ek[k] - 1);
            }
            sidc = ws0 + segl;
            bmc  = __ballot(l < 16 && c < nvA && flag);
            nvc  = nvA;
        }

        unsigned short* Lc = &lds[w][0][0];
        unsigned short* Lp = &lds[w][1][0];

        // produce tile 0 into Lc (unoverlapped)
        {
            bf16x8 af[2];
            {
                bf16x8 f; unsigned* fu = (unsigned*)&f;
                fu[0] = cvt2(x0.x, x0.y); fu[1] = cvt2(x0.z, x0.w);
                fu[2] = cvt2(x1.x, x1.y); fu[3] = cvt2(x1.z, x1.w);
                af[0] = f;
                fu[0] = cvt2(x2.x, x2.y); fu[1] = cvt2(x2.z, x2.w);
                fu[2] = cvt2(x3.x, x3.y); fu[3] = cvt2(x3.z, x3.w);
                af[1] = f;
            }
            f32x4 z = {0.f, 0.f, 0.f, 0.f};
            z = __builtin_amdgcn_mfma_f32_16x16x32_bf16(af[0], wf[0][0], z, 0, 0, 0);
            f32x4 acc0 = __builtin_amdgcn_mfma_f32_16x16x32_bf16(af[1], wf[0][1], z, 0, 0, 0);
            float s0 = acc0[0] + bT[0];
            float s1 = s0 + acc0[1] + bT[0];
            float s2 = s1 + acc0[2] + bT[0];
            float s3 = s2 + acc0[3] + bT[0];
            float uu = s3;
            float v16 = __shfl_up(uu, 16, 64);
            float v32 = __shfl_up(uu, 32, 64);
            float v48 = __shfl_up(uu, 48, 64);
            float excl = (q >= 1 ? v16 : 0.f) + (q >= 2 ? v32 : 0.f) + (q >= 3 ? v48 : 0.f);
            Pc0 = excl + s0; Pc1 = excl + s1; Pc2 = excl + s2; Pc3 = excl + s3;
            #pragma unroll
            for (int T = 1; T <= 9; ++T) {
                f32x4 zz2 = {0.f, 0.f, 0.f, 0.f};
                zz2 = __builtin_amdgcn_mfma_f32_16x16x32_bf16(af[0], wf[T][0], zz2, 0, 0, 0);
                f32x4 a2 = __builtin_amdgcn_mfma_f32_16x16x32_bf16(af[1], wf[T][1], zz2, 0, 0, 0);
                prodT(T, a2, Lc);
            }
            diagpost(Lc);
        }

        // ---------------- main pipelined loop ----------------
        while (gN < gend) {
            wave_lds_sync();                 // retire produce writes for consume reads
            // rotate prefetched data
            x0 = y0; x1 = y1; x2 = y2; x3 = y3;
            const int gCur = gN;
            const int nvn = min(16, gend - gCur);
            gN = gCur + nvn;
            // issue gather for tile k+2
            const int idx2 = min(gN + c, gend - 1);
            const int p2 = sorted[idx2];
            const float* d2 = data + (size_t)p2 * DIM + 8 * q;
            y0 = ((const float4*)d2)[0]; y1 = ((const float4*)d2)[1];
            y2 = ((const float4*)(d2 + 32))[0]; y3 = ((const float4*)(d2 + 32))[1];
            // meta for produce tile (indices idxB)
            int segl = 0; bool flag = false;
            #pragma unroll
            for (int k = 0; k < SEGW; ++k) {
                segl += (idxB >= Ek[k]) ? 1 : 0;
                flag |= (idxB == Ek[k] - 1);
            }
            const int sidn = ws0 + segl;
            const unsigned long long bmn = __ballot(l < 16 && c < nvn && flag);
            idxB = idx2;

            // produce head: A-frags + T=0 + t prefix
            bf16x8 af[2];
            {
                bf16x8 f; unsigned* fu = (unsigned*)&f;
                fu[0] = cvt2(x0.x, x0.y); fu[1] = cvt2(x0.z, x0.w);
                fu[2] = cvt2(x1.x, x1.y); fu[3] = cvt2(x1.z, x1.w);
                af[0] = f;
                fu[0] = cvt2(x2.x, x2.y); fu[1] = cvt2(x2.z, x2.w);
                fu[2] = cvt2(x3.x, x3.y); fu[3] = cvt2(x3.z, x3.w);
                af[1] = f;
            }
            f32x4 z = {0.f, 0.f, 0.f, 0.f};
            z = __builtin_amdgcn_mfma_f32_16x16x32_bf16(af[0], wf[0][0], z, 0, 0, 0);
            f32x4 acc0 = __builtin_amdgcn_mfma_f32_16x16x32_bf16(af[1], wf[0][1], z, 0, 0, 0);
            float s0 = acc0[0] + bT[0];
            float s1 = s0 + acc0[1] + bT[0];
            float s2 = s1 + acc0[2] + bT[0];
            float s3 = s2 + acc0[3] + bT[0];
            float uu = s3;
            float v16 = __shfl_up(uu, 16, 64);
            float v32 = __shfl_up(uu, 32, 64);
            float v48 = __shfl_up(uu, 48, 64);
            float excl = (q >= 1 ? v16 : 0.f) + (q >= 2 ? v32 : 0.f) + (q >= 3 ? v48 : 0.f);
            const float Pn0 = excl + s0, Pn1 = excl + s1, Pn2 = excl + s2, Pn3 = excl + s3;

            // fused: produce T=u into Lp, consume pair u-1 from Lc (nv=16 tile)
            #pragma unroll
            for (int u = 1; u <= 9; ++u) {
                f32x4 zz2 = {0.f, 0.f, 0.f, 0.f};
                zz2 = __builtin_amdgcn_mfma_f32_16x16x32_bf16(af[0], wf[u][0], zz2, 0, 0, 0);
                f32x4 a2 = __builtin_amdgcn_mfma_f32_16x16x32_bf16(af[1], wf[u][1], zz2, 0, 0, 0);
                prodT(u, a2, Lp);
                if (u <= 8) consPair(u - 1, Lc);
            }
            diagpost(Lp);

            // consume tail: carry open segment's t partial (consumed tile: nv=16)
            if (a_start < 16) {
                const int ii = 15;
                float Pi = __shfl(Pc3, 48 | c, 64);
                float Pe = 0.f;
                if (a_start > 0) {
                    const int aa = a_start - 1, ra = aa & 3;
                    float va = (ra == 0) ? Pc0 : (ra == 1) ? Pc1 : (ra == 2) ? Pc2 : Pc3;
                    Pe = __shfl(va, ((aa >> 2) << 4) | c, 64);
                }
                tcarry += Pi - Pe;
                (void)ii;
            }
            a_start = 0;

            // shift meta; swap buffers
            Pc0 = Pn0; Pc1 = Pn1; Pc2 = Pn2; Pc3 = Pn3;
            bmc = bmn; sidc = sidn; nvc = nvn;
            unsigned short* tt = Lc; Lc = Lp; Lp = tt;
        }

        // ---------------- epilogue: consume last tile (may be short) ----------------
        wave_lds_sync();
        const int npair = (nvc + 1) >> 1;
        for (int j = 0; j < npair; ++j) {
            const int i0 = 2 * j, i1 = i0 + 1;
            bf16x8 lf = *(const bf16x8*)(Lc + i0 * 256 + lofs);
            const bool vld1 = (i1 < nvc);
            const bool f0 = (bmc >> i0) & 1;
            if (vld1 && !f0) {
                if (j & 1) fb = __builtin_amdgcn_mfma_f32_16x16x32_bf16(lf, lf, fb, 0, 0, 0);
                else       fa = __builtin_amdgcn_mfma_f32_16x16x32_bf16(lf, lf, fa, 0, 0, 0);
                if ((bmc >> i1) & 1) flushC(i1);
            } else {
                const bf16x8 zz = {0, 0, 0, 0, 0, 0, 0, 0};
                bf16x8 lo = (q < 2) ? lf : zz;
                fa = __builtin_amdgcn_mfma_f32_16x16x32_bf16(lo, lo, fa, 0, 0, 0);
                if (f0) flushC(i0);
                if (vld1) {
                    bf16x8 hi = (q >= 2) ? lf : zz;
                    fb = __builtin_amdgcn_mfma_f32_16x16x32_bf16(hi, hi, fb, 0, 0, 0);
                    if ((bmc >> i1) & 1) flushC(i1);
                }
            }
        }
        // last segment always ends at gend -> last point flushed; no carry needed
    }
}

// ---------------------------------------------------------------------------
// seg: per-thread packed Cholesky solve + GEMV (verified; + empty-seg guard)
// ---------------------------------------------------------------------------
__global__ __launch_bounds__(256, 2)
void seg_kernel(const float* __restrict__ Fred,
                const float* __restrict__ tred,
                const int*   __restrict__ cnt,
                const float* __restrict__ projW,
                float* __restrict__ out)
{
    const int s = blockIdx.x * 256 + threadIdx.x;
    if (s >= NSEG) return;
    float* orow = out + (size_t)s * OUTD;

    if (cnt[s] == 0) {   // empty segment: F=I, t=0 -> out=0 (Fred row is poison)
        float4 zz = {0.f, 0.f, 0.f, 0.f};
        #pragma unroll
        for (int oc = 0; oc < OUTD; oc += 4) *(float4*)(orow + oc) = zz;
        return;
    }

    float a[NTRI];
    const float4* f4 = (const float4*)(Fred + (size_t)s * NTRI);
    #pragma unroll
    for (int qq = 0; qq < NTRI / 4; ++qq) {
        float4 v = f4[qq];
        a[4 * qq + 0] = v.x; a[4 * qq + 1] = v.y;
        a[4 * qq + 2] = v.z; a[4 * qq + 3] = v.w;
    }
    #pragma unroll
    for (int ii = 0; ii < INNER; ++ii) a[tri(ii) + ii] += 1.0f;

    #pragma unroll
    for (int j = 0; j < INNER; ++j) {
        float d = a[tri(j) + j];
        #pragma unroll
        for (int k = 0; k < j; ++k)
            d = fmaf(-a[tri(j) + k], a[tri(j) + k], d);
        d = sqrtf(d);
        a[tri(j) + j] = d;
        float dinv = __fdividef(1.0f, d);
        #pragma unroll
        for (int ii = j + 1; ii < INNER; ++ii) {
            float v = a[tri(ii) + j];
            #pragma unroll
            for (int k = 0; k < j; ++k)
                v = fmaf(-a[tri(ii) + k], a[tri(j) + k], v);
            a[tri(ii) + j] = v * dinv;
        }
    }
    float z[INNER];
    #pragma unroll
    for (int ii = 0; ii < INNER; ++ii) {
        float v = 1.0f;
        #pragma unroll
        for (int k = 0; k < ii; ++k)
            v = fmaf(-a[tri(ii) + k], z[k], v);
        z[ii] = __fdividef(v, a[tri(ii) + ii]);
    }
    float x[INNER];
    #pragma unroll
    for (int ii = INNER - 1; ii >= 0; --ii) {
        float v = z[ii];
        #pragma unroll
        for (int k = ii + 1; k < INNER; ++k)
            v = fmaf(-a[tri(k) + ii], x[k], v);
        x[ii] = __fdividef(v, a[tri(ii) + ii]);
    }
    float theta[INNER];
    const float4* t4 = (const float4*)(tred + (size_t)s * INNER);
    #pragma unroll
    for (int qq = 0; qq < 4; ++qq) {
        float4 v = t4[qq];
        theta[4 * qq + 0] = v.x * x[4 * qq + 0];
        theta[4 * qq + 1] = v.y * x[4 * qq + 1];
        theta[4 * qq + 2] = v.z * x[4 * qq + 2];
        theta[4 * qq + 3] = v.w * x[4 * qq + 3];
    }
    for (int oc = 0; oc < OUTD; oc += 8) {
        float acc[8] = {0, 0, 0, 0, 0, 0, 0, 0};
        #pragma unroll
        for (int j = 0; j < INNER; ++j) {
            float th = theta[j];
            #pragma unroll
            for (int uu = 0; uu < 8; ++uu)
                acc[uu] = fmaf(th, projW[j * OUTD + oc + uu], acc[uu]);
        }
        float4 v0 = {acc[0], acc[1], acc[2], acc[3]};
        float4 v1 = {acc[4], acc[5], acc[6], acc[7]};
        ((float4*)(orow + oc))[0] = v0;
        ((float4*)(orow + oc))[1] = v1;
    }
}

extern "C" void kernel_launch(void* const* d_in, const int* in_sizes, int n_in,
                              void* d_out, int out_size, void* d_ws, size_t ws_size,
                              hipStream_t stream)
{
    const float* data  = (const float*)d_in[0];
    const int*   segs  = (const int*)d_in[1];
    const float* W     = (const float*)d_in[3];
    const float* bias  = (const float*)d_in[4];
    const float* projW = (const float*)d_in[5];

    int* cnt     = (int*)d_ws;                        // NSEG
    int* off     = cnt + NSEG;                        // NSEG
    int* bsum    = off + NSEG;                        // 512
    int* rank    = bsum + 512;                        // N_PTS
    int* sorted  = rank + N_PTS;                      // N_PTS
    float* Fred  = (float*)(sorted + N_PTS);          // NSEG*NTRI
    float* tred  = Fred + (size_t)NSEG * NTRI;        // NSEG*INNER

    hipMemsetAsync(cnt, 0, NSEG * sizeof(int), stream);

    hist_kernel   <<<(N_PTS + 255) / 256, 256, 0, stream>>>(segs, cnt, rank);
    scan_blocks   <<<NB, 256, 0, stream>>>(cnt, off, bsum);
    scan_top      <<<1, 512, 0, stream>>>(bsum);
    scan_add      <<<NB, 256, 0, stream>>>(off, bsum);
    scatter_kernel<<<(N_PTS + 255) / 256, 256, 0, stream>>>(segs, off, rank, sorted);
    main_kernel   <<<MAINB, 256, 0, stream>>>(data, sorted, off, W, bias, Fred, tred);
    seg_kernel    <<<NB, 256, 0, stream>>>(Fred, tred, cnt, projW, (float*)d_out);
}

// Round 7
// 576.168 us; speedup vs baseline: 1.6588x; 1.6588x over previous
//
#include <hip/hip_runtime.h>
#include <hip/hip_bf16.h>

// Fishnet round 10: hybrid W split (regs + LDS) to reach 3 waves/SIMD.
//   Register model (r6-r9, confirmed): waves/SIMD = floor(512/(arch+AGPR)).
//   wf[10][2]=80 AGPR pinned all reg-variants at 2 waves/SIMD; r8 (all-W-in-LDS)
//   reached 3 but starved arch regs (68) with serial ds_read->MFMA. Hybrid:
//   - wf[0..4] in AGPR (40), wf[5..9] in block-shared LDS (10KB), depth-1
//     prefetched ds_read_b128 (conflict-free, 4-iter lead) off critical path.
//   - launch_bounds(256,3): total ~150 < 170 budget; LDS 42KB -> 3 blocks/CU.
//   - two-tile-ahead sorted[] prefetch: data gather issues at tile top with
//     row ids already resident (removes 200-600cy sorted-wait from the chain).
//   - Ek from off[s+1] (== off[s]+cnt[s]); main no longer reads cnt/segs.
//   - r9's full pipeline REVERTED (spill: WRITE 60->335MB).
// Aux: hist/scan/scatter counting sort + per-thread Cholesky seg solve (verified).

#define N_PTS   1000000
#define DIM     64
#define INNER   16
#define OUTD    64
#define NSEG    100000
#define NTRI    136
#define NET_OUT 152
#define NB      391          // ceil(NSEG/256)
#define SEGW    7            // segments per wave in main_kernel
#define NWAVES  ((NSEG + SEGW - 1) / SEGW)
#define MAINB   ((NWAVES + 3) / 4)

typedef short bf16x8 __attribute__((ext_vector_type(8)));
typedef float f32x4  __attribute__((ext_vector_type(4)));
typedef float f32x2  __attribute__((ext_vector_type(2)));
typedef __bf16 bfv2  __attribute__((ext_vector_type(2)));

__device__ __host__ __forceinline__ constexpr int tri(int i) { return i * (i + 1) / 2; }

__device__ __forceinline__ float fast_tanh(float x) {
    float e = __expf(2.0f * x);
    return 1.0f - __fdividef(2.0f, e + 1.0f);
}
__device__ __forceinline__ float fast_softplus(float x) {
    return __logf(1.0f + __expf(x));
}
// native RNE fp32 -> bf16 (v_cvt_pk_bf16_f32 on gfx950)
__device__ __forceinline__ unsigned short cvt1(float f) {
    __bf16 h = (__bf16)f;
    return __builtin_bit_cast(unsigned short, h);
}
__device__ __forceinline__ unsigned cvt2(float a, float b) {
    f32x2 t; t[0] = a; t[1] = b;
    bfv2 h = __builtin_convertvector(t, bfv2);
    return __builtin_bit_cast(unsigned, h);
}

// in-wave LDS producer->consumer ordering (validated round 2)
__device__ __forceinline__ void wave_lds_sync() {
    __builtin_amdgcn_wave_barrier();
    __builtin_amdgcn_s_waitcnt(0xC07F);   // lgkmcnt(0)
    __builtin_amdgcn_wave_barrier();
}

__device__ __forceinline__ void ecoord(int e, int& r, int& c, bool& dg) {
    int rr = 0;
    #pragma unroll
    for (int k = 1; k < 16; ++k) rr = (e >= tri(k)) ? k : rr;
    r = rr; c = e - tri(rr); dg = (c == rr);
}

// ---------------------------------------------------------------------------
__global__ __launch_bounds__(256) void hist_kernel(const int* __restrict__ segs,
                                                   int* __restrict__ cnt,
                                                   int* __restrict__ rank)
{
    int t = blockIdx.x * 256 + threadIdx.x;
    if (t < N_PTS) rank[t] = atomicAdd(&cnt[segs[t]], 1);
}

__global__ __launch_bounds__(256) void scan_blocks(const int* __restrict__ cnt,
                                                   int* __restrict__ off,
                                                   int* __restrict__ bsum)
{
    __shared__ int sh[256];
    const int t = threadIdx.x;
    const int i = blockIdx.x * 256 + t;
    int v = (i < NSEG) ? cnt[i] : 0;
    sh[t] = v;
    __syncthreads();
    #pragma unroll
    for (int d = 1; d < 256; d <<= 1) {
        int add = (t >= d) ? sh[t - d] : 0;
        __syncthreads();
        sh[t] += add;
        __syncthreads();
    }
    if (i < NSEG) off[i] = sh[t] - v;
    if (t == 255) bsum[blockIdx.x] = sh[t];
}

__global__ __launch_bounds__(512) void scan_top(int* __restrict__ bsum)
{
    __shared__ int sh[512];
    const int t = threadIdx.x;
    int v = (t < NB) ? bsum[t] : 0;
    sh[t] = v;
    __syncthreads();
    #pragma unroll
    for (int d = 1; d < 512; d <<= 1) {
        int add = (t >= d) ? sh[t - d] : 0;
        __syncthreads();
        sh[t] += add;
        __syncthreads();
    }
    if (t < NB) bsum[t] = sh[t] - v;
}

__global__ __launch_bounds__(256) void scan_add(int* __restrict__ off,
                                                const int* __restrict__ bsum)
{
    int i = blockIdx.x * 256 + threadIdx.x;
    if (i < NSEG) off[i] += bsum[blockIdx.x];
}

__global__ __launch_bounds__(256) void scatter_kernel(const int* __restrict__ segs,
                                                      const int* __restrict__ off,
                                                      const int* __restrict__ rank,
                                                      int* __restrict__ sorted)
{
    int t = blockIdx.x * 256 + threadIdx.x;
    if (t < N_PTS) sorted[off[segs[t]] + rank[t]] = t;
}

// ---------------------------------------------------------------------------
// main: one wave per SEGW consecutive segments; hybrid W cache.
// ---------------------------------------------------------------------------
__global__ __launch_bounds__(256, 3)
void main_kernel(const float* __restrict__ data,
                 const int*   __restrict__ sorted,
                 const int*   __restrict__ off,
                 const float* __restrict__ W,
                 const float* __restrict__ bias,
                 float* __restrict__ Fred,
                 float* __restrict__ tred)
{
    // block-shared upper-half W: slabs s5=(T-5)*2+ks, each 64 lanes x 16B = 1KB
    __shared__ __align__(16) unsigned short Wl[10 * 512];
    // per wave: 16 points x (16 rows x 16 cols bf16, contiguous) = 8192 B
    __shared__ __align__(16) unsigned short lds[4 * 4096];
    const int l = threadIdx.x & 63;
    const int w = threadIdx.x >> 6;
    unsigned short* Lw = &lds[w * 4096];
    const int c = l & 15;          // col-in-tile / D-col / A-row
    const int q = l >> 4;          // quad

    // ---- W upper half (T=5..9) -> LDS, block-cooperative; before any exit ----
    for (int s5 = w; s5 < 10; s5 += 4) {
        const int T = 5 + (s5 >> 1), ks = s5 & 1;
        bf16x8 f;
        #pragma unroll
        for (int j = 0; j < 8; ++j) {
            int k = 32 * ks + 8 * q + j;
            int n = 16 * T + c;
            f[j] = (n < NET_OUT) ? (short)cvt1(W[k * NET_OUT + n]) : (short)0;
        }
        *(bf16x8*)(Wl + s5 * 512 + l * 8) = f;
    }
    // zero L image (per-wave region): strict-upper stays zero forever
    #pragma unroll
    for (int u = 0; u < 32; ++u) ((unsigned*)Lw)[u * 64 + l] = 0u;
    __syncthreads();

    const int wave_id = blockIdx.x * 4 + w;
    const int ws0 = wave_id * SEGW;
    if (ws0 >= NSEG) return;
    const int ws1 = min(ws0 + SEGW, NSEG);

    // ---- wave-owned segment end offsets (off[s+1] == off[s]+cnt[s]) ----
    int Ek[SEGW];
    #pragma unroll
    for (int k = 0; k < SEGW; ++k) {
        const int s = ws0 + k;
        Ek[k] = (s < ws1) ? ((s + 1 < NSEG) ? off[s + 1] : N_PTS) : 0x7fffffff;
    }
    const int gend = (ws1 < NSEG) ? off[ws1] : N_PTS;
    int g = off[ws0];
    if (g >= gend) return;         // all owned segments empty

    // ---- register half of W (T=0..4) + bias ----
    bf16x8 wf[5][2];
    float  bT[10];
    #pragma unroll
    for (int T = 0; T < 5; ++T) {
        #pragma unroll
        for (int ks = 0; ks < 2; ++ks) {
            bf16x8 f;
            #pragma unroll
            for (int j = 0; j < 8; ++j) {
                int k = 32 * ks + 8 * q + j;
                int n = 16 * T + c;
                f[j] = (short)cvt1(W[k * NET_OUT + n]);   // n<152 always for T<5
            }
            wf[T][ks] = f;
        }
    }
    #pragma unroll
    for (int T = 0; T < 10; ++T) {
        int n = 16 * T + c;
        bT[T] = (n < NET_OUT) ? bias[n] : 0.0f;
    }

    // ---- per-lane entry coords for T=1..9 (e = 16*(T-1)+c), stride 16 ----
    int rcoff[9];
    int dgmask = 0, dgoff0 = 0;
    #pragma unroll
    for (int T = 1; T <= 9; ++T) {
        int e = 16 * (T - 1) + c;
        int re, ce; bool dg;
        ecoord(e, re, ce, dg);
        rcoff[T - 1] = re * 16 + ce;
        if (dg && (T < 9 || c < 8)) {
            dgmask |= 1 << T;
            if (T <= 8) dgoff0 = re * 16 + ce;
        }
    }
    const bool v9     = (c < 8);       // T=9 valid only for c<8 (e<136)
    const bool hasdg0 = (c != 15);
    const int  qb     = q << 10;       // q*1024 ushorts = row (4q) base

    f32x4 fa = {0.f, 0.f, 0.f, 0.f};
    f32x4 fb = {0.f, 0.f, 0.f, 0.f};
    float tcarry = 0.f;
    int a_start = 0;
    float dsv0 = 0.f, dsv1 = 0.f, dsv2 = 0.f, dsv3 = 0.f;

    // F-loop LDS offset: quad 0-1 -> point i, 2-3 -> point i+1
    const int lofs = c * 16 + (q & 1) * 8 + (q >> 1) * 256;
    const unsigned short* Wp = Wl + l * 8;   // per-lane LDS-W fragment base

    // ---- prologue: tile0 data + tile1 row ids (two-ahead pipeline) ----
    int idxA = min(g + c, gend - 1);
    const int pA = sorted[idxA];
    const float* dA = data + (size_t)pA * DIM + 8 * q;
    float4 x0 = ((const float4*)dA)[0], x1 = ((const float4*)dA)[1];
    float4 x2 = ((const float4*)(dA + 32))[0], x3 = ((const float4*)(dA + 32))[1];
    int idxB = min(g + 16 + c, gend - 1);
    int pB   = sorted[idxB];

    while (g < gend) {
        const int nv = min(16, gend - g);
        const int gn = g + nv;
        // issue next-tile data gathers (row ids pB already resident)
        const float* dB = data + (size_t)pB * DIM + 8 * q;
        float4 y0 = ((const float4*)dB)[0], y1 = ((const float4*)dB)[1];
        float4 y2 = ((const float4*)(dB + 32))[0], y3 = ((const float4*)(dB + 32))[1];
        // issue row ids for tile k+2 (clamped; unused if past gend)
        const int idxC = min(gn + 16 + c, gend - 1);
        const int pC   = sorted[idxC];

        // ---- sid + boundary flag from Ek registers (current tile: idxA) ----
        int segl = 0;
        bool flag = false;
        #pragma unroll
        for (int k = 0; k < SEGW; ++k) {
            segl += (idxA >= Ek[k]) ? 1 : 0;
            flag |= (idxA == Ek[k] - 1);
        }
        const int sidv = ws0 + segl;
        const unsigned long long bm = __ballot(l < 16 && c < nv && flag);

        // ---- A-frags from current tile's (already-loaded) data rows ----
        bf16x8 af[2];
        {
            bf16x8 f; unsigned* fu = (unsigned*)&f;
            fu[0] = cvt2(x0.x, x0.y); fu[1] = cvt2(x0.z, x0.w);
            fu[2] = cvt2(x1.x, x1.y); fu[3] = cvt2(x1.z, x1.w);
            af[0] = f;
            fu[0] = cvt2(x2.x, x2.y); fu[1] = cvt2(x2.z, x2.w);
            fu[2] = cvt2(x3.x, x3.y); fu[3] = cvt2(x3.z, x3.w);
            af[1] = f;
        }

        // ---- T=0: t head ----
        f32x4 acc0;
        {
            f32x4 z = {0.f, 0.f, 0.f, 0.f};
            z = __builtin_amdgcn_mfma_f32_16x16x32_bf16(af[0], wf[0][0], z, 0, 0, 0);
            acc0 = __builtin_amdgcn_mfma_f32_16x16x32_bf16(af[1], wf[0][1], z, 0, 0, 0);
        }

        // ---- t prefix along point index m (rows of D tile 0) ----
        float s0 = acc0[0] + bT[0];
        float s1 = s0 + acc0[1] + bT[0];
        float s2 = s1 + acc0[2] + bT[0];
        float s3 = s2 + acc0[3] + bT[0];
        float u  = s3;
        float v16 = __shfl_up(u, 16, 64);
        float v32 = __shfl_up(u, 32, 64);
        float v48 = __shfl_up(u, 48, 64);
        float excl = (q >= 1 ? v16 : 0.f) + (q >= 2 ? v32 : 0.f) + (q >= 3 ? v48 : 0.f);
        float P0 = excl + s0, P1 = excl + s1, P2 = excl + s2, P3 = excl + s3;

        // ---- T=1..9 fused: net MFMA -> tanh -> L image in LDS ----
        // W operand: regs for T<=4, LDS (depth-1 prefetch, 4-iter lead) for T>=5.
        wave_lds_sync();                       // WAR vs previous tile's F reads
        bf16x8 wna = *(const bf16x8*)(Wp);           // T=5 ks0 (slab 0)
        bf16x8 wnb = *(const bf16x8*)(Wp + 512);     // T=5 ks1 (slab 1)
        #pragma unroll
        for (int T = 1; T <= 9; ++T) {
            bf16x8 wa, wb;
            if (T <= 4) { wa = wf[T][0]; wb = wf[T][1]; }
            else {
                wa = wna; wb = wnb;
                if (T < 9) {
                    wna = *(const bf16x8*)(Wp + (T - 4) * 1024);         // slab (T+1-5)*2
                    wnb = *(const bf16x8*)(Wp + (T - 4) * 1024 + 512);   // slab ..+1
                }
            }
            f32x4 z = {0.f, 0.f, 0.f, 0.f};
            z = __builtin_amdgcn_mfma_f32_16x16x32_bf16(af[0], wa, z, 0, 0, 0);
            f32x4 a2 = __builtin_amdgcn_mfma_f32_16x16x32_bf16(af[1], wb, z, 0, 0, 0);
            const bool isdg = (dgmask >> T) & 1;
            const bool st   = (T < 9 || v9) && !isdg;
            unsigned short* bp = Lw + (qb + rcoff[T - 1]);
            #pragma unroll
            for (int r = 0; r < 4; ++r) {
                float v = fast_tanh(a2[r] + bT[T]);
                if (st) bp[r * 256] = cvt1(v);
                if (T <= 8) {
                    if (r == 0) dsv0 = isdg ? v : dsv0;
                    if (r == 1) dsv1 = isdg ? v : dsv1;
                    if (r == 2) dsv2 = isdg ? v : dsv2;
                    if (r == 3) dsv3 = isdg ? v : dsv3;
                }
            }
            if (T == 9 && (c == 7)) {   // second diagonal (15,15) for c==7 lanes
                unsigned short* dp9 = Lw + (qb + 255);
                #pragma unroll
                for (int r = 0; r < 4; ++r) {
                    float v = fast_tanh(a2[r] + bT[9]);
                    dp9[r * 256] = cvt1(fast_softplus(v));
                }
            }
        }
        // diag post-pass: softplus on saved fp32 tanh (identical arithmetic)
        if (hasdg0) {
            unsigned short* dp0 = Lw + (qb + dgoff0);
            dp0[0]   = cvt1(fast_softplus(dsv0));
            dp0[256] = cvt1(fast_softplus(dsv1));
            dp0[512] = cvt1(fast_softplus(dsv2));
            dp0[768] = cvt1(fast_softplus(dsv3));
        }
        wave_lds_sync();                       // RAW: writes visible to F reads

        auto flush = [&](int i) {
            const int sid = __shfl(sidv, i, 64);
            const int rs = i & 3;
            float vi = (rs == 0) ? P0 : (rs == 1) ? P1 : (rs == 2) ? P2 : P3;
            float Pi = __shfl(vi, ((i >> 2) << 4) | c, 64);
            float Pe = 0.f;
            if (a_start > 0) {
                const int aa = a_start - 1, ra = aa & 3;
                float va = (ra == 0) ? P0 : (ra == 1) ? P1 : (ra == 2) ? P2 : P3;
                Pe = __shfl(va, ((aa >> 2) << 4) | c, 64);
            }
            float ts = Pi - Pe + tcarry;
            if (l < 16) tred[(size_t)sid * INNER + c] = ts;
            tcarry = 0.f;
            f32x4 ft = fa + fb;
            #pragma unroll
            for (int r = 0; r < 4; ++r) {
                const int mr = 4 * q + r;
                if (c <= mr)
                    Fred[(size_t)sid * NTRI + tri(mr) + c] = ft[r];
            }
            fa = (f32x4){0.f, 0.f, 0.f, 0.f};
            fb = (f32x4){0.f, 0.f, 0.f, 0.f};
            a_start = i + 1;
        };

        // ---- pair-packed F MFMA: K=32 covers two points; dual accumulators ----
        const int npair = (nv + 1) >> 1;
        for (int j = 0; j < npair; ++j) {
            const int i0 = 2 * j, i1 = i0 + 1;
            bf16x8 lf = *(const bf16x8*)(Lw + i0 * 256 + lofs);
            const bool vld1 = (i1 < nv);
            const bool f0 = (bm >> i0) & 1;
            if (vld1 && !f0) {
                // fast path: both points in same segment
                if (j & 1) fb = __builtin_amdgcn_mfma_f32_16x16x32_bf16(lf, lf, fb, 0, 0, 0);
                else       fa = __builtin_amdgcn_mfma_f32_16x16x32_bf16(lf, lf, fa, 0, 0, 0);
                if ((bm >> i1) & 1) flush(i1);
            } else {
                // boundary inside the pair, or odd tail: masked single-point MFMAs
                const bf16x8 zz = {0, 0, 0, 0, 0, 0, 0, 0};
                bf16x8 lo = (q < 2) ? lf : zz;
                fa = __builtin_amdgcn_mfma_f32_16x16x32_bf16(lo, lo, fa, 0, 0, 0);
                if (f0) flush(i0);
                if (vld1) {
                    bf16x8 hi = (q >= 2) ? lf : zz;
                    fb = __builtin_amdgcn_mfma_f32_16x16x32_bf16(hi, hi, fb, 0, 0, 0);
                    if ((bm >> i1) & 1) flush(i1);
                }
            }
        }

        // carry open segment's t partial into next tile
        if (a_start < nv) {
            const int ii = nv - 1, rs = ii & 3;
            float vi = (rs == 0) ? P0 : (rs == 1) ? P1 : (rs == 2) ? P2 : P3;
            float Pi = __shfl(vi, ((ii >> 2) << 4) | c, 64);
            float Pe = 0.f;
            if (a_start > 0) {
                const int aa = a_start - 1, ra = aa & 3;
                float va = (ra == 0) ? P0 : (ra == 1) ? P1 : (ra == 2) ? P2 : P3;
                Pe = __shfl(va, ((aa >> 2) << 4) | c, 64);
            }
            tcarry += Pi - Pe;
        }
        a_start = 0;
        g = gn; idxA = idxB; idxB = idxC; pB = pC;
        x0 = y0; x1 = y1; x2 = y2; x3 = y3;   // rotate prefetched data
    }
}

// ---------------------------------------------------------------------------
// seg: per-thread packed Cholesky solve + GEMV (verified; + empty-seg guard)
// ---------------------------------------------------------------------------
__global__ __launch_bounds__(256, 2)
void seg_kernel(const float* __restrict__ Fred,
                const float* __restrict__ tred,
                const int*   __restrict__ cnt,
                const float* __restrict__ projW,
                float* __restrict__ out)
{
    const int s = blockIdx.x * 256 + threadIdx.x;
    if (s >= NSEG) return;
    float* orow = out + (size_t)s * OUTD;

    if (cnt[s] == 0) {   // empty segment: F=I, t=0 -> out=0 (Fred row is poison)
        float4 zz = {0.f, 0.f, 0.f, 0.f};
        #pragma unroll
        for (int oc = 0; oc < OUTD; oc += 4) *(float4*)(orow + oc) = zz;
        return;
    }

    float a[NTRI];
    const float4* f4 = (const float4*)(Fred + (size_t)s * NTRI);
    #pragma unroll
    for (int qq = 0; qq < NTRI / 4; ++qq) {
        float4 v = f4[qq];
        a[4 * qq + 0] = v.x; a[4 * qq + 1] = v.y;
        a[4 * qq + 2] = v.z; a[4 * qq + 3] = v.w;
    }
    #pragma unroll
    for (int ii = 0; ii < INNER; ++ii) a[tri(ii) + ii] += 1.0f;

    #pragma unroll
    for (int j = 0; j < INNER; ++j) {
        float d = a[tri(j) + j];
        #pragma unroll
        for (int k = 0; k < j; ++k)
            d = fmaf(-a[tri(j) + k], a[tri(j) + k], d);
        d = sqrtf(d);
        a[tri(j) + j] = d;
        float dinv = __fdividef(1.0f, d);
        #pragma unroll
        for (int ii = j + 1; ii < INNER; ++ii) {
            float v = a[tri(ii) + j];
            #pragma unroll
            for (int k = 0; k < j; ++k)
                v = fmaf(-a[tri(ii) + k], a[tri(j) + k], v);
            a[tri(ii) + j] = v * dinv;
        }
    }
    float z[INNER];
    #pragma unroll
    for (int ii = 0; ii < INNER; ++ii) {
        float v = 1.0f;
        #pragma unroll
        for (int k = 0; k < ii; ++k)
            v = fmaf(-a[tri(ii) + k], z[k], v);
        z[ii] = __fdividef(v, a[tri(ii) + ii]);
    }
    float x[INNER];
    #pragma unroll
    for (int ii = INNER - 1; ii >= 0; --ii) {
        float v = z[ii];
        #pragma unroll
        for (int k = ii + 1; k < INNER; ++k)
            v = fmaf(-a[tri(k) + ii], x[k], v);
        x[ii] = __fdividef(v, a[tri(ii) + ii]);
    }
    float theta[INNER];
    const float4* t4 = (const float4*)(tred + (size_t)s * INNER);
    #pragma unroll
    for (int qq = 0; qq < 4; ++qq) {
        float4 v = t4[qq];
        theta[4 * qq + 0] = v.x * x[4 * qq + 0];
        theta[4 * qq + 1] = v.y * x[4 * qq + 1];
        theta[4 * qq + 2] = v.z * x[4 * qq + 2];
        theta[4 * qq + 3] = v.w * x[4 * qq + 3];
    }
    for (int oc = 0; oc < OUTD; oc += 8) {
        float acc[8] = {0, 0, 0, 0, 0, 0, 0, 0};
        #pragma unroll
        for (int j = 0; j < INNER; ++j) {
            float th = theta[j];
            #pragma unroll
            for (int uu = 0; uu < 8; ++uu)
                acc[uu] = fmaf(th, projW[j * OUTD + oc + uu], acc[uu]);
        }
        float4 v0 = {acc[0], acc[1], acc[2], acc[3]};
        float4 v1 = {acc[4], acc[5], acc[6], acc[7]};
        ((float4*)(orow + oc))[0] = v0;
        ((float4*)(orow + oc))[1] = v1;
    }
}

extern "C" void kernel_launch(void* const* d_in, const int* in_sizes, int n_in,
                              void* d_out, int out_size, void* d_ws, size_t ws_size,
                              hipStream_t stream)
{
    const float* data  = (const float*)d_in[0];
    const int*   segs  = (const int*)d_in[1];
    const float* W     = (const float*)d_in[3];
    const float* bias  = (const float*)d_in[4];
    const float* projW = (const float*)d_in[5];

    int* cnt     = (int*)d_ws;                        // NSEG
    int* off     = cnt + NSEG;                        // NSEG
    int* bsum    = off + NSEG;                        // 512
    int* rank    = bsum + 512;                        // N_PTS
    int* sorted  = rank + N_PTS;                      // N_PTS
    float* Fred  = (float*)(sorted + N_PTS);          // NSEG*NTRI
    float* tred  = Fred + (size_t)NSEG * NTRI;        // NSEG*INNER

    hipMemsetAsync(cnt, 0, NSEG * sizeof(int), stream);

    hist_kernel   <<<(N_PTS + 255) / 256, 256, 0, stream>>>(segs, cnt, rank);
    scan_blocks   <<<NB, 256, 0, stream>>>(cnt, off, bsum);
    scan_top      <<<1, 512, 0, stream>>>(bsum);
    scan_add      <<<NB, 256, 0, stream>>>(off, bsum);
    scatter_kernel<<<(N_PTS + 255) / 256, 256, 0, stream>>>(segs, off, rank, sorted);
    main_kernel   <<<MAINB, 256, 0, stream>>>(data, sorted, off, W, bias, Fred, tred);
    seg_kernel    <<<NB, 256, 0, stream>>>(Fred, tred, cnt, projW, (float*)d_out);
}